// Round 15
// baseline (229.511 us; speedup 1.0000x reference)
//
#include <hip/hip_runtime.h>

// ---------------------------------------------------------------------------
// MaskedSuperAttention (agent attention), B=4 N=16384 C=512 H=8 HD=64 NA=32
// Math (R9): score1 = x·(Wk@a^T), score2 = x·(Wq@a^T) => Q,K,V never hit HBM.
// R15 = R14 + pre-kernel fusion: k_cvt_x / k_w_t_p / k_prep (independent)
// merged into one k_pre launch (block-range dispatch) -> 2 fewer gaps and the
// small prep work runs concurrently under the BW-bound cvt stream.
//   k_pre        : blocks [0,16384): x f32 -> xt bf16 TILED
//                  blocks [16384,16576): Wv/Sk/Sq -> wtl2 tiled-swizzled
//                  blocks [16576,16832): Wproj -> Wpt bf16 [n][k]
//   k_qkvs       : GEMM x@[Wv|akw|aqw] (BN=128) ; epilogue: flash partial
//                  (M,L,PV f32) per 128-tok chunk + q-softmax -> Qat tiled.
//   k_agent_comb : merge 128 partials per (b,h) -> agent_v bf16 (R14 wave-par)
//   k_avp        : AVP = agent_v @ Wproj -> AVPt TILED (grid 4x32)
//   k_out        : out = (Qattn @ AVPt) * keymask
// bf16 tile layout: 128x64 (16KiB); byte(row,c8)= row*128 + ((c8^(row&7))<<4)
// ---------------------------------------------------------------------------

typedef float  f32x4   __attribute__((ext_vector_type(4)));
typedef short  bf16x8  __attribute__((ext_vector_type(8)));
typedef unsigned short u16x4 __attribute__((ext_vector_type(4)));
typedef unsigned short u16x8 __attribute__((ext_vector_type(8)));

#define MFMA16(a, b, c) __builtin_amdgcn_mfma_f32_16x16x32_bf16((a), (b), (c), 0, 0, 0)

__device__ __forceinline__ unsigned short f2bf(float f) {
    unsigned u = __builtin_bit_cast(unsigned, f);
    u += 0x7FFFu + ((u >> 16) & 1u);        // RTNE
    return (unsigned short)(u >> 16);
}
__device__ __forceinline__ void gl2lds16(const void* g, void* l) {
    __builtin_amdgcn_global_load_lds(
        (const __attribute__((address_space(1))) unsigned int*)g,
        (__attribute__((address_space(3))) unsigned int*)l, 16, 0, 0);
}

// ------------------------------- k_pre --------------------------------------
// grid 16832, block 256. Three independent jobs by block range (see header).
__global__ __launch_bounds__(256) void k_pre(const float* __restrict__ x,
                                             const float* __restrict__ at,
                                             const float* __restrict__ Wq,
                                             const float* __restrict__ Wk,
                                             const float* __restrict__ Wv,
                                             const float* __restrict__ Wp,
                                             unsigned char* __restrict__ xt,
                                             unsigned char* __restrict__ wtl2,
                                             unsigned short* __restrict__ Wpt) {
    __shared__ float t[32][33];
    const int bid = blockIdx.x;
    if (bid < 16384) {
        // ---- cvt_x: x f32 -> xt bf16 tiled ----
        int v = bid * 256 + threadIdx.x;
        int tile = v >> 10;
        int q = v & 1023;
        int row = q >> 3, c = q & 7;
        int mt = tile >> 3, ks = tile & 7;
        const float* sp = x + ((size_t)(mt * 128 + row)) * 512 + ks * 64 + c * 8;
        float4 v0 = *(const float4*)sp;
        float4 v1 = *(const float4*)(sp + 4);
        u16x8 o;
        o[0] = f2bf(v0.x); o[1] = f2bf(v0.y); o[2] = f2bf(v0.z); o[3] = f2bf(v0.w);
        o[4] = f2bf(v1.x); o[5] = f2bf(v1.y); o[6] = f2bf(v1.z); o[7] = f2bf(v1.w);
        *(u16x8*)(xt + (size_t)tile * 16384 + row * 128 + ((c ^ (row & 7)) << 4)) = o;
    } else if (bid < 16576) {
        // ---- prep: wtl2 tile group (nt,ks): z=0 Wv; z=1 Sk; z=2 Sq ----
        const int idx = bid - 16384;
        const int ks = idx & 7, nt = (idx >> 3) & 7, z = idx >> 6;
        if (z == 0) {
            unsigned char* dst = wtl2 + ((size_t)(nt * 8 + ks)) * 16384;
            const int row = threadIdx.x & 63;
#pragma unroll
            for (int cc = 0; cc < 2; ++cc) {
                int c = (threadIdx.x >> 6) + cc * 4;
                u16x8 o;
#pragma unroll
                for (int j = 0; j < 8; ++j)
                    o[j] = f2bf(Wv[(size_t)(ks * 64 + c * 8 + j) * 512 + nt * 64 + row]);
                *(u16x8*)(dst + row * 128 + ((c ^ (row & 7)) << 4)) = o;
            }
        } else {
            const float* W = (z == 2) ? Wq : Wk;
            const int h = nt;
            const int row = threadIdx.x >> 3, c8 = threadIdx.x & 7;
            const float* ar = at + row * 512 + h * 64;
            float accv[8];
#pragma unroll
            for (int j = 0; j < 8; ++j) {
                const float* wr = W + (size_t)(ks * 64 + c8 * 8 + j) * 512 + h * 64;
                float s = 0.f;
#pragma unroll 8
                for (int d = 0; d < 64; ++d) s += ar[d] * wr[d];
                accv[j] = s;
            }
            u16x8 o;
#pragma unroll
            for (int j = 0; j < 8; ++j) o[j] = f2bf(accv[j]);
            *(u16x8*)(wtl2 + ((size_t)(h * 8 + ks)) * 16384 + 8192 + (z - 1) * 4096 +
                      row * 128 + ((c8 ^ (row & 7)) << 4)) = o;
        }
    } else {
        // ---- w_t_p: Wproj [k][n] -> Wpt [n][k] ----
        const int idx2 = bid - 16576;
        const int n0 = (idx2 & 15) * 32, k0 = (idx2 >> 4) * 32;
#pragma unroll
        for (int j = 0; j < 4; ++j) {
            int i = threadIdx.x + 256 * j;
            int ky = i >> 5, nx = i & 31;
            t[ky][nx] = Wp[(size_t)(k0 + ky) * 512 + n0 + nx];
        }
        __syncthreads();
#pragma unroll
        for (int j = 0; j < 4; ++j) {
            int i = threadIdx.x + 256 * j;
            int ny = i >> 5, kx = i & 31;
            Wpt[(size_t)(n0 + ny) * 512 + k0 + kx] = f2bf(t[kx][ny]);
        }
    }
}

// ------------------------------- k_qkvs --------------------------------------
// BM=128, BN=128 (V64, Sk32, Sq32), BK=64, 2x2 wave grid (R10-proven).
// grid 4096 (XCD-swz), block 256, LDS 32768. f32 partials.
__global__ __launch_bounds__(256) void k_qkvs(const unsigned char* __restrict__ xt,
                                              const unsigned char* __restrict__ wtl2,
                                              const int* __restrict__ mask,
                                              unsigned char* __restrict__ Qat,
                                              float* __restrict__ part_pv,
                                              float* __restrict__ part_ml) {
    __shared__ __align__(16) unsigned char S_[32768];
    unsigned char* As = S_;                 // [0,16K) main A
    unsigned char* Bs = S_ + 16384;         // [16K,32K) main B
    const int tid = threadIdx.x, l = tid & 63, wid = tid >> 6;
    const int g = l >> 4, lr = l & 15;
    const int wm = wid >> 1, wn = wid & 1;
    const int dd = blockIdx.x;
    const int nt = (dd >> 3) & 7;
    const int mt = (dd & 7) + ((dd >> 6) << 3);
    const int m0 = mt * 128;
    const int b = mt >> 7, chunk = mt & 127, bh = b * 8 + nt;

    f32x4 acc[4][4] = {};

    for (int ks = 0; ks < 8; ++ks) {
        const size_t abase = ((size_t)(mt * 8 + ks)) * 16384;
        const size_t bbase = ((size_t)(nt * 8 + ks)) * 16384;
#pragma unroll
        for (int i = 0; i < 4; ++i)
            gl2lds16(xt + abase + i * 4096 + tid * 16, As + i * 4096 + tid * 16);
#pragma unroll
        for (int i = 0; i < 4; ++i)
            gl2lds16(wtl2 + bbase + i * 4096 + tid * 16, Bs + i * 4096 + tid * 16);
        __syncthreads();

        bf16x8 af[4][2];
#pragma unroll
        for (int mf = 0; mf < 4; ++mf) {
            int row = wm * 64 + mf * 16 + lr;
#pragma unroll
            for (int k2 = 0; k2 < 2; ++k2)
                af[mf][k2] = *(const bf16x8*)(As + row * 128 + (((k2 * 4 + g) ^ (row & 7)) << 4));
        }
#pragma unroll
        for (int k2 = 0; k2 < 2; ++k2) {
#pragma unroll
            for (int nf = 0; nf < 4; ++nf) {
                // wn=0: V cols (regio 0); wn=1: nf 0,1 -> Sk; nf 2,3 -> Sq
                const int regio = wn ? (8192 + (nf >> 1) * 4096) : 0;
                const int brow = (wn ? ((nf & 1) * 16) : (nf * 16)) + lr;
                bf16x8 bv = *(const bf16x8*)(Bs + regio + brow * 128 +
                                             (((k2 * 4 + g) ^ (brow & 7)) << 4));
#pragma unroll
                for (int mf = 0; mf < 4; ++mf)
                    acc[mf][nf] = MFMA16(af[mf][k2], bv, acc[mf][nf]);
            }
        }
        __syncthreads();
    }

    // ---------------- epilogue (R10-proven layout) ----------------
    // LDS: P [2 halves][32 ag][144B] @0..9216 ; Ev [2][64 d][144B] @9216..27648
    //      redM [2][32] @27648 ; redL [2][32] @27904 ; avsH overlays [0,16K).
    unsigned char* Ph0 = S_;
    unsigned char* Evh = S_ + 9216;
    float* redM = (float*)(S_ + 27648);
    float* redL = (float*)(S_ + 27904);
    float* avsH = (float*)S_;

    float sc2[4][2][4];
    float Mb[2];

    if (wn == 0) {
        // ---- V waves: acc[mf][vf] -> Ev half wm ([64 d][64 tok], stride 144) ----
        unsigned char* Ev = Evh + wm * 9216;
#pragma unroll
        for (int mf = 0; mf < 4; ++mf)
#pragma unroll
            for (int vf = 0; vf < 4; ++vf) {
                int d5 = vf * 16 + lr;
                u16x4 vv;
                vv[0] = f2bf(acc[mf][vf][0]); vv[1] = f2bf(acc[mf][vf][1]);
                vv[2] = f2bf(acc[mf][vf][2]); vv[3] = f2bf(acc[mf][vf][3]);
                *(u16x4*)(Ev + d5 * 144 + mf * 32 + g * 8) = vv;
            }
    } else {
        // ---- score waves: q-softmax from Sq (acc[mf][2..3]) -> Qat tiled ----
        const size_t qbase = ((size_t)(mt * 4 + (nt >> 1))) * 16384;
        const int c80 = (nt & 1) * 4 + (lr >> 3);
#pragma unroll
        for (int mf = 0; mf < 4; ++mf) {
#pragma unroll
            for (int r = 0; r < 4; ++r) {
                float v0 = acc[mf][2][r] * 0.125f, v1 = acc[mf][3][r] * 0.125f;
                float m = fmaxf(v0, v1);
                m = fmaxf(m, __shfl_xor(m, 1));
                m = fmaxf(m, __shfl_xor(m, 2));
                m = fmaxf(m, __shfl_xor(m, 4));
                m = fmaxf(m, __shfl_xor(m, 8));
                float e0 = __expf(v0 - m), e1 = __expf(v1 - m);
                float s = e0 + e1;
                s += __shfl_xor(s, 1);
                s += __shfl_xor(s, 2);
                s += __shfl_xor(s, 4);
                s += __shfl_xor(s, 8);
                float inv = 1.0f / s;
                int row = wm * 64 + mf * 16 + g * 4 + r;
                size_t rb = qbase + row * 128 + (lr & 7) * 2;
                *(unsigned short*)(Qat + rb + ((c80 ^ (row & 7)) << 4)) = f2bf(e0 * inv);
                *(unsigned short*)(Qat + rb + (((c80 + 2) ^ (row & 7)) << 4)) = f2bf(e1 * inv);
            }
        }
        // ---- masked key scores (acc[mf][0..1]) + wave max per agent ----
#pragma unroll
        for (int mf = 0; mf < 4; ++mf) {
            int4 mv = *(const int4*)(mask + m0 + wm * 64 + mf * 16 + g * 4);
            int mvr[4] = {mv.x, mv.y, mv.z, mv.w};
#pragma unroll
            for (int sf = 0; sf < 2; ++sf)
#pragma unroll
                for (int r = 0; r < 4; ++r)
                    sc2[mf][sf][r] = (mvr[r] > 0) ? acc[mf][sf][r] * 0.125f : -1.0e9f;
        }
#pragma unroll
        for (int sf = 0; sf < 2; ++sf) {
            float m = sc2[0][sf][0];
#pragma unroll
            for (int mf = 0; mf < 4; ++mf)
#pragma unroll
                for (int r = 0; r < 4; ++r) m = fmaxf(m, sc2[mf][sf][r]);
            m = fmaxf(m, __shfl_xor(m, 16));
            m = fmaxf(m, __shfl_xor(m, 32));
            if (g == 0) redM[wm * 32 + sf * 16 + lr] = m;
        }
    }
    __syncthreads();    // redM + Ev visible

    if (wn == 1) {
        // ---- block max, P = exp(s-Mb) -> P LDS (u16x4), L partials ----
        float le[2] = {0.f, 0.f};
#pragma unroll
        for (int sf = 0; sf < 2; ++sf) {
            int ag = sf * 16 + lr;
            Mb[sf] = fmaxf(redM[ag], redM[32 + ag]);
        }
        unsigned char* Ph = Ph0 + wm * 4608;
#pragma unroll
        for (int mf = 0; mf < 4; ++mf)
#pragma unroll
            for (int sf = 0; sf < 2; ++sf) {
                u16x4 p4;
#pragma unroll
                for (int r = 0; r < 4; ++r) {
                    float p = __expf(sc2[mf][sf][r] - Mb[sf]);
                    le[sf] += p;
                    p4[r] = f2bf(p);
                }
                int ag = sf * 16 + lr;
                *(u16x4*)(Ph + ag * 144 + mf * 32 + g * 8) = p4;
            }
#pragma unroll
        for (int sf = 0; sf < 2; ++sf) {
            le[sf] += __shfl_xor(le[sf], 16);
            le[sf] += __shfl_xor(le[sf], 32);
            if (g == 0) redL[wm * 32 + sf * 16 + lr] = le[sf];
        }
    }
    __syncthreads();    // P + redL visible

    // ---- PV: each wave one K=32 slice (half=wm, ks-sub=wn) ----
    const unsigned char* Ph = Ph0 + wm * 4608;
    const unsigned char* Ev = Evh + wm * 9216;
    bf16x8 pa[2];
#pragma unroll
    for (int agf = 0; agf < 2; ++agf) {
        int ag = agf * 16 + lr;
        pa[agf] = *(const bf16x8*)(Ph + ag * 144 + wn * 64 + g * 16);
    }
    f32x4 pv[2][4] = {};
#pragma unroll
    for (int vf = 0; vf < 4; ++vf) {
        int d5 = vf * 16 + lr;
        bf16x8 bv = *(const bf16x8*)(Ev + d5 * 144 + wn * 64 + g * 16);
#pragma unroll
        for (int agf = 0; agf < 2; ++agf)
            pv[agf][vf] = MFMA16(pa[agf], bv, pv[agf][vf]);
    }
    __syncthreads();    // PV reads done; safe to overlay avsH

    // ---- cross-wave PV reduce (2 rounds of 16 agents), f32 out ----
    float* pout = part_pv + ((size_t)bh * 128 + chunk) * 2048;
#pragma unroll
    for (int agf = 0; agf < 2; ++agf) {
#pragma unroll
        for (int vf = 0; vf < 4; ++vf)
#pragma unroll
            for (int r = 0; r < 4; ++r)
                avsH[wid * 1024 + (g * 4 + r) * 64 + vf * 16 + lr] = pv[agf][vf][r];
        __syncthreads();
#pragma unroll
        for (int j = 0; j < 4; ++j) {
            int idx = tid + 256 * j;
            pout[agf * 1024 + idx] = avsH[idx] + avsH[1024 + idx] +
                                     avsH[2048 + idx] + avsH[3072 + idx];
        }
        if (agf == 0) __syncthreads();
    }
    // ---- M,L partials ----
    if (wid == 1 && g == 0) {
        size_t o = ((size_t)bh * 128 + chunk) * 64;
        float L0 = redL[lr] + redL[32 + lr];
        float L1 = redL[16 + lr] + redL[48 + lr];
        part_ml[o + lr * 2] = Mb[0];
        part_ml[o + lr * 2 + 1] = L0;
        part_ml[o + (16 + lr) * 2] = Mb[1];
        part_ml[o + (16 + lr) * 2 + 1] = L1;
    }
}

// ------------------------------- k_agent_comb --------------------------------
// merge 128 chunks per (b,h). grid (8 agent-groups, 32 bh), block 256.
// R14: one wave per agent — parallel M/L via shfl butterfly, scl lane-wise
// (no barrier needed), dual-accumulator unroll-8 main reduce.
__global__ __launch_bounds__(256) void k_agent_comb(const float* __restrict__ part_pv,
                                                    const float* __restrict__ part_ml,
                                                    unsigned short* __restrict__ avbf) {
    __shared__ float scl[4][128];
    const int tid = threadIdx.x;
    const int ag0 = blockIdx.x * 4, bh = blockIdx.y;
    const int agl = tid >> 6;           // 0..3 : one wave per agent
    const int lane = tid & 63;
    const int ag = ag0 + agl;
    const float* mlb = part_ml + (size_t)bh * 8192 + ag * 2;

    float m0v = mlb[(size_t)lane * 64];
    float l0v = mlb[(size_t)lane * 64 + 1];
    float m1v = mlb[(size_t)(lane + 64) * 64];
    float l1v = mlb[(size_t)(lane + 64) * 64 + 1];
    float M = fmaxf(m0v, m1v);
#pragma unroll
    for (int k = 1; k < 64; k <<= 1) M = fmaxf(M, __shfl_xor(M, k));

    float e0 = __expf(m0v - M), e1 = __expf(m1v - M);
    scl[agl][lane] = e0;
    scl[agl][lane + 64] = e1;
    float L = e0 * l0v + e1 * l1v;
#pragma unroll
    for (int k = 1; k < 64; k <<= 1) L += __shfl_xor(L, k);
    const float iL = 1.0f / L;

    const int d5 = lane;
    const float* pv = part_pv + (size_t)bh * 128 * 2048 + (size_t)ag * 64 + d5;
    const float* sr = &scl[agl][0];
    float a0 = 0.f, a1 = 0.f;
#pragma unroll 8
    for (int c = 0; c < 128; c += 2) {
        a0 += sr[c] * pv[(size_t)c * 2048];
        a1 += sr[c + 1] * pv[(size_t)(c + 1) * 2048];
    }
    avbf[(size_t)bh * 2048 + (size_t)ag * 64 + d5] = f2bf((a0 + a1) * iL);
}

// ------------------------------- k_avp ----------------------------------------
// grid (4 nf-quarters, 32 bh), block 64.
__global__ __launch_bounds__(64) void k_avp(const unsigned short* __restrict__ avbf,
                                            const unsigned short* __restrict__ Wpt,
                                            unsigned char* __restrict__ AVPt) {
    const int l = threadIdx.x & 63;
    const int q = blockIdx.x, bh = blockIdx.y, b = bh >> 3, h = bh & 7;
    const int g = l >> 4, lr = l & 15;
    bf16x8 avf[2][2];
#pragma unroll
    for (int mf = 0; mf < 2; ++mf)
#pragma unroll
        for (int ks = 0; ks < 2; ++ks)
            avf[mf][ks] = *(const bf16x8*)(avbf + (size_t)bh * 2048 + (mf * 16 + lr) * 64 + ks * 32 + g * 8);
    const int kst = h >> 1;
#pragma unroll
    for (int nf = q * 8; nf < q * 8 + 8; ++nf) {
        int j = nf * 16 + lr;
        bf16x8 w0 = *(const bf16x8*)(Wpt + (size_t)j * 512 + h * 64 + g * 8);
        bf16x8 w1 = *(const bf16x8*)(Wpt + (size_t)j * 512 + h * 64 + 32 + g * 8);
        int jt = j >> 7, row = j & 127;
#pragma unroll
        for (int mf = 0; mf < 2; ++mf) {
            f32x4 z = {0.f, 0.f, 0.f, 0.f};
            f32x4 acc = MFMA16(avf[mf][0], w0, z);
            acc = MFMA16(avf[mf][1], w1, acc);
            u16x4 o;
            o[0] = f2bf(acc[0]); o[1] = f2bf(acc[1]); o[2] = f2bf(acc[2]); o[3] = f2bf(acc[3]);
            int c8 = (h & 1) * 4 + mf * 2 + (g >> 1);
            size_t byte = ((size_t)((b * 4 + jt) * 4 + kst)) * 16384 + row * 128 +
                          ((c8 ^ (row & 7)) << 4) + (g & 1) * 8;
            *(u16x4*)(AVPt + byte) = o;
        }
    }
}

// ------------------------------- k_out -----------------------------------------
__global__ __launch_bounds__(256) void k_out(const unsigned char* __restrict__ Qat,
                                             const unsigned char* __restrict__ AVPt,
                                             const int* __restrict__ mask,
                                             float* __restrict__ out) {
    __shared__ __align__(16) unsigned char As[16384];
    __shared__ __align__(16) unsigned char Bs[16384];
    const int tid = threadIdx.x, l = tid & 63, wid = tid >> 6;
    const int wm = wid >> 1, wn = wid & 1;
    const int g = l >> 4, lr = l & 15;
    const int d = blockIdx.x;
    const int nt = (d >> 3) & 3;
    const int mt = (d & 7) + ((d >> 5) << 3);
    const int m0 = mt * 128, j0 = nt * 128;
    const int b = m0 >> 14;
    f32x4 acc[4][4] = {};

    for (int ks = 0; ks < 4; ++ks) {
        const size_t abase = ((size_t)(mt * 4 + ks)) * 16384;
        const size_t bbase = ((size_t)((b * 4 + nt) * 4 + ks)) * 16384;
#pragma unroll
        for (int i = 0; i < 4; ++i) {
            gl2lds16(Qat + abase + i * 4096 + tid * 16, As + i * 4096 + tid * 16);
            gl2lds16(AVPt + bbase + i * 4096 + tid * 16, Bs + i * 4096 + tid * 16);
        }
        __syncthreads();
        bf16x8 af[4][2];
#pragma unroll
        for (int mf = 0; mf < 4; ++mf) {
            int row = wm * 64 + mf * 16 + lr;
#pragma unroll
            for (int k2 = 0; k2 < 2; ++k2)
                af[mf][k2] = *(const bf16x8*)(As + row * 128 + (((k2 * 4 + g) ^ (row & 7)) << 4));
        }
#pragma unroll
        for (int k2 = 0; k2 < 2; ++k2) {
#pragma unroll
            for (int nf = 0; nf < 4; ++nf) {
                int brow = wn * 64 + nf * 16 + lr;
                bf16x8 bv = *(const bf16x8*)(Bs + brow * 128 + (((k2 * 4 + g) ^ (brow & 7)) << 4));
#pragma unroll
                for (int mf = 0; mf < 4; ++mf)
                    acc[mf][nf] = MFMA16(af[mf][k2], bv, acc[mf][nf]);
            }
        }
        __syncthreads();
    }
#pragma unroll
    for (int mf = 0; mf < 4; ++mf) {
        int trow = m0 + wm * 64 + mf * 16 + g * 4;
#pragma unroll
        for (int r = 0; r < 4; ++r) {
            float mv = (mask[trow + r] > 0) ? 1.0f : 0.0f;
#pragma unroll
            for (int nf = 0; nf < 4; ++nf) {
                int j = j0 + wn * 64 + nf * 16 + lr;
                out[(size_t)(trow + r) * 512 + j] = acc[mf][nf][r] * mv;
            }
        }
    }
}

// ------------------------------- launch -----------------------------------------
extern "C" void kernel_launch(void* const* d_in, const int* in_sizes, int n_in,
                              void* d_out, int out_size, void* d_ws, size_t ws_size,
                              hipStream_t stream) {
    const float* x  = (const float*)d_in[0];
    const int*  mk  = (const int*)d_in[1];
    const float* at = (const float*)d_in[2];
    const float* Wq = (const float*)d_in[3];
    const float* Wk = (const float*)d_in[4];
    const float* Wv = (const float*)d_in[5];
    const float* Wp = (const float*)d_in[6];
    float* out = (float*)d_out;
    char* ws = (char*)d_ws;

    unsigned char*  xt     = (unsigned char*)(ws);                        // [0,64) tiled x
    float* part_pv = (float*)(ws + ((size_t)64 << 20));                   // [64,98) 33.5 MiB f32
    float* part_ml = (float*)(ws + ((size_t)100 << 20));                  // [100,101) 1 MiB
    unsigned char*  Qat    = (unsigned char*)(ws + ((size_t)192 << 20));  // [192,224) tiled
    unsigned short* Wpt    = (unsigned short*)(ws + ((size_t)256 << 20)); // [256,256.5)
    unsigned char*  wtl2   = (unsigned char*)(ws + ((size_t)258 << 20));  // [258,259) 1 MiB
    unsigned short* avbf   = (unsigned short*)(ws + ((size_t)259 << 20) + (576 << 10));
    unsigned char*  AVPt   = (unsigned char*)(ws + ((size_t)260 << 20));  // [260,261)

    k_pre<<<16832, 256, 0, stream>>>(x, at, Wq, Wk, Wv, Wp, xt, wtl2, Wpt);
    k_qkvs<<<4096, 256, 0, stream>>>(xt, wtl2, mk, Qat, part_pv, part_ml);
    k_agent_comb<<<dim3(8, 32), 256, 0, stream>>>(part_pv, part_ml, avbf);
    k_avp<<<dim3(4, 32), 64, 0, stream>>>(avbf, Wpt, AVPt);
    k_out<<<2048, 256, 0, stream>>>(Qat, AVPt, mk, out);
}

// Round 16
// 211.695 us; speedup vs baseline: 1.0842x; 1.0842x over previous
//
#include <hip/hip_runtime.h>

// ---------------------------------------------------------------------------
// MaskedSuperAttention (agent attention), B=4 N=16384 C=512 H=8 HD=64 NA=32
// Math (R9): score1 = x·(Wk@a^T), score2 = x·(Wq@a^T) => Q,K,V never hit HBM.
// R16 = R14 tail (fusion reverted) + k_cvt_x grid-stride rewrite:
// R15's counters exposed cvt as ~100us latency/launch-bound (16384 tiny
// blocks, 2-deep MLP). Now grid 2048, 8 chunks/thread, unroll-4 -> deep MLP.
//   k_cvt_x      : x f32 -> xt bf16 TILED (grid-stride, 2048 blocks)
//   k_w_t_p      : Wproj -> Wpt bf16 [n][k] (for k_avp)
//   k_prep       : z=0: Wv -> wtl2 V region ; z=1,2: Sk/Sq = W@a^T regions
//   k_qkvs       : GEMM x@[Wv|akw|aqw] (BN=128) ; epilogue: flash partial
//                  (M,L,PV f32) per 128-tok chunk + q-softmax -> Qat tiled.
//   k_agent_comb : merge 128 partials per (b,h) -> agent_v bf16 (R14 wave-par)
//   k_avp        : AVP = agent_v @ Wproj -> AVPt TILED (grid 4x32)
//   k_out        : out = (Qattn @ AVPt) * keymask
// bf16 tile layout: 128x64 (16KiB); byte(row,c8)= row*128 + ((c8^(row&7))<<4)
// ---------------------------------------------------------------------------

typedef float  f32x4   __attribute__((ext_vector_type(4)));
typedef short  bf16x8  __attribute__((ext_vector_type(8)));
typedef unsigned short u16x4 __attribute__((ext_vector_type(4)));
typedef unsigned short u16x8 __attribute__((ext_vector_type(8)));

#define MFMA16(a, b, c) __builtin_amdgcn_mfma_f32_16x16x32_bf16((a), (b), (c), 0, 0, 0)

__device__ __forceinline__ unsigned short f2bf(float f) {
    unsigned u = __builtin_bit_cast(unsigned, f);
    u += 0x7FFFu + ((u >> 16) & 1u);        // RTNE
    return (unsigned short)(u >> 16);
}
__device__ __forceinline__ void gl2lds16(const void* g, void* l) {
    __builtin_amdgcn_global_load_lds(
        (const __attribute__((address_space(1))) unsigned int*)g,
        (__attribute__((address_space(3))) unsigned int*)l, 16, 0, 0);
}

// ------------------------------- k_cvt_x -----------------------------------
// grid 2048 (8 blocks/CU), block 256; each thread handles 8 chunks of
// (2x float4 -> u16x8). unroll 4 keeps ~8 loads in flight.
__global__ __launch_bounds__(256) void k_cvt_x(const float* __restrict__ x,
                                               unsigned char* __restrict__ xt) {
    const int base = blockIdx.x * 256 + threadIdx.x;
#pragma unroll 4
    for (int it = 0; it < 8; ++it) {
        int v = it * 524288 + base;          // 8 x 2048 x 256 = 4.19M chunks
        int tile = v >> 10;
        int q = v & 1023;
        int row = q >> 3, c = q & 7;
        int mt = tile >> 3, ks = tile & 7;
        const float* sp = x + ((size_t)(mt * 128 + row)) * 512 + ks * 64 + c * 8;
        float4 v0 = *(const float4*)sp;
        float4 v1 = *(const float4*)(sp + 4);
        u16x8 o;
        o[0] = f2bf(v0.x); o[1] = f2bf(v0.y); o[2] = f2bf(v0.z); o[3] = f2bf(v0.w);
        o[4] = f2bf(v1.x); o[5] = f2bf(v1.y); o[6] = f2bf(v1.z); o[7] = f2bf(v1.w);
        *(u16x8*)(xt + (size_t)tile * 16384 + row * 128 + ((c ^ (row & 7)) << 4)) = o;
    }
}

// ------------------------------- k_w_t_p ------------------------------------
__global__ __launch_bounds__(256) void k_w_t_p(const float* __restrict__ Wp,
                                               unsigned short* __restrict__ Wpt) {
    __shared__ float t[32][33];
    const int k0 = blockIdx.y * 32, n0 = blockIdx.x * 32;
#pragma unroll
    for (int j = 0; j < 4; ++j) {
        int i = threadIdx.x + 256 * j;
        int ky = i >> 5, nx = i & 31;
        t[ky][nx] = Wp[(size_t)(k0 + ky) * 512 + n0 + nx];
    }
    __syncthreads();
#pragma unroll
    for (int j = 0; j < 4; ++j) {
        int i = threadIdx.x + 256 * j;
        int ny = i >> 5, kx = i & 31;
        Wpt[(size_t)(n0 + ny) * 512 + k0 + kx] = f2bf(t[kx][ny]);
    }
}

// ------------------------------- k_prep --------------------------------------
// grid (8 ks, 8 nt/h, 3): z=0: Wv tile -> wtl2 [0,8K) of group (nt,ks);
// z=1: Sk = Wk@a^T -> [8K,12K) ; z=2: Sq = Wq@a^T -> [12K,16K).
__global__ __launch_bounds__(256) void k_prep(const float* __restrict__ Wv,
                                              const float* __restrict__ at,
                                              const float* __restrict__ Wk,
                                              const float* __restrict__ Wq,
                                              unsigned char* __restrict__ wtl2) {
    const int ks = blockIdx.x, nt = blockIdx.y, z = blockIdx.z;
    if (z == 0) {
        unsigned char* dst = wtl2 + ((size_t)(nt * 8 + ks)) * 16384;
        const int row = threadIdx.x & 63;
#pragma unroll
        for (int cc = 0; cc < 2; ++cc) {
            int c = (threadIdx.x >> 6) + cc * 4;
            u16x8 o;
#pragma unroll
            for (int j = 0; j < 8; ++j)
                o[j] = f2bf(Wv[(size_t)(ks * 64 + c * 8 + j) * 512 + nt * 64 + row]);
            *(u16x8*)(dst + row * 128 + ((c ^ (row & 7)) << 4)) = o;
        }
    } else {
        const float* W = (z == 2) ? Wq : Wk;
        const int h = nt;
        const int row = threadIdx.x >> 3, c8 = threadIdx.x & 7;
        const float* ar = at + row * 512 + h * 64;
        float accv[8];
#pragma unroll
        for (int j = 0; j < 8; ++j) {
            const float* wr = W + (size_t)(ks * 64 + c8 * 8 + j) * 512 + h * 64;
            float s = 0.f;
#pragma unroll 8
            for (int d = 0; d < 64; ++d) s += ar[d] * wr[d];
            accv[j] = s;
        }
        u16x8 o;
#pragma unroll
        for (int j = 0; j < 8; ++j) o[j] = f2bf(accv[j]);
        *(u16x8*)(wtl2 + ((size_t)(h * 8 + ks)) * 16384 + 8192 + (z - 1) * 4096 +
                  row * 128 + ((c8 ^ (row & 7)) << 4)) = o;
    }
}

// ------------------------------- k_qkvs --------------------------------------
// BM=128, BN=128 (V64, Sk32, Sq32), BK=64, 2x2 wave grid (R10-proven).
// grid 4096 (XCD-swz), block 256, LDS 32768. f32 partials.
__global__ __launch_bounds__(256) void k_qkvs(const unsigned char* __restrict__ xt,
                                              const unsigned char* __restrict__ wtl2,
                                              const int* __restrict__ mask,
                                              unsigned char* __restrict__ Qat,
                                              float* __restrict__ part_pv,
                                              float* __restrict__ part_ml) {
    __shared__ __align__(16) unsigned char S_[32768];
    unsigned char* As = S_;                 // [0,16K) main A
    unsigned char* Bs = S_ + 16384;         // [16K,32K) main B
    const int tid = threadIdx.x, l = tid & 63, wid = tid >> 6;
    const int g = l >> 4, lr = l & 15;
    const int wm = wid >> 1, wn = wid & 1;
    const int dd = blockIdx.x;
    const int nt = (dd >> 3) & 7;
    const int mt = (dd & 7) + ((dd >> 6) << 3);
    const int m0 = mt * 128;
    const int b = mt >> 7, chunk = mt & 127, bh = b * 8 + nt;

    f32x4 acc[4][4] = {};

    for (int ks = 0; ks < 8; ++ks) {
        const size_t abase = ((size_t)(mt * 8 + ks)) * 16384;
        const size_t bbase = ((size_t)(nt * 8 + ks)) * 16384;
#pragma unroll
        for (int i = 0; i < 4; ++i)
            gl2lds16(xt + abase + i * 4096 + tid * 16, As + i * 4096 + tid * 16);
#pragma unroll
        for (int i = 0; i < 4; ++i)
            gl2lds16(wtl2 + bbase + i * 4096 + tid * 16, Bs + i * 4096 + tid * 16);
        __syncthreads();

        bf16x8 af[4][2];
#pragma unroll
        for (int mf = 0; mf < 4; ++mf) {
            int row = wm * 64 + mf * 16 + lr;
#pragma unroll
            for (int k2 = 0; k2 < 2; ++k2)
                af[mf][k2] = *(const bf16x8*)(As + row * 128 + (((k2 * 4 + g) ^ (row & 7)) << 4));
        }
#pragma unroll
        for (int k2 = 0; k2 < 2; ++k2) {
#pragma unroll
            for (int nf = 0; nf < 4; ++nf) {
                // wn=0: V cols (regio 0); wn=1: nf 0,1 -> Sk; nf 2,3 -> Sq
                const int regio = wn ? (8192 + (nf >> 1) * 4096) : 0;
                const int brow = (wn ? ((nf & 1) * 16) : (nf * 16)) + lr;
                bf16x8 bv = *(const bf16x8*)(Bs + regio + brow * 128 +
                                             (((k2 * 4 + g) ^ (brow & 7)) << 4));
#pragma unroll
                for (int mf = 0; mf < 4; ++mf)
                    acc[mf][nf] = MFMA16(af[mf][k2], bv, acc[mf][nf]);
            }
        }
        __syncthreads();
    }

    // ---------------- epilogue (R10-proven layout) ----------------
    // LDS: P [2 halves][32 ag][144B] @0..9216 ; Ev [2][64 d][144B] @9216..27648
    //      redM [2][32] @27648 ; redL [2][32] @27904 ; avsH overlays [0,16K).
    unsigned char* Ph0 = S_;
    unsigned char* Evh = S_ + 9216;
    float* redM = (float*)(S_ + 27648);
    float* redL = (float*)(S_ + 27904);
    float* avsH = (float*)S_;

    float sc2[4][2][4];
    float Mb[2];

    if (wn == 0) {
        // ---- V waves: acc[mf][vf] -> Ev half wm ([64 d][64 tok], stride 144) ----
        unsigned char* Ev = Evh + wm * 9216;
#pragma unroll
        for (int mf = 0; mf < 4; ++mf)
#pragma unroll
            for (int vf = 0; vf < 4; ++vf) {
                int d5 = vf * 16 + lr;
                u16x4 vv;
                vv[0] = f2bf(acc[mf][vf][0]); vv[1] = f2bf(acc[mf][vf][1]);
                vv[2] = f2bf(acc[mf][vf][2]); vv[3] = f2bf(acc[mf][vf][3]);
                *(u16x4*)(Ev + d5 * 144 + mf * 32 + g * 8) = vv;
            }
    } else {
        // ---- score waves: q-softmax from Sq (acc[mf][2..3]) -> Qat tiled ----
        const size_t qbase = ((size_t)(mt * 4 + (nt >> 1))) * 16384;
        const int c80 = (nt & 1) * 4 + (lr >> 3);
#pragma unroll
        for (int mf = 0; mf < 4; ++mf) {
#pragma unroll
            for (int r = 0; r < 4; ++r) {
                float v0 = acc[mf][2][r] * 0.125f, v1 = acc[mf][3][r] * 0.125f;
                float m = fmaxf(v0, v1);
                m = fmaxf(m, __shfl_xor(m, 1));
                m = fmaxf(m, __shfl_xor(m, 2));
                m = fmaxf(m, __shfl_xor(m, 4));
                m = fmaxf(m, __shfl_xor(m, 8));
                float e0 = __expf(v0 - m), e1 = __expf(v1 - m);
                float s = e0 + e1;
                s += __shfl_xor(s, 1);
                s += __shfl_xor(s, 2);
                s += __shfl_xor(s, 4);
                s += __shfl_xor(s, 8);
                float inv = 1.0f / s;
                int row = wm * 64 + mf * 16 + g * 4 + r;
                size_t rb = qbase + row * 128 + (lr & 7) * 2;
                *(unsigned short*)(Qat + rb + ((c80 ^ (row & 7)) << 4)) = f2bf(e0 * inv);
                *(unsigned short*)(Qat + rb + (((c80 + 2) ^ (row & 7)) << 4)) = f2bf(e1 * inv);
            }
        }
        // ---- masked key scores (acc[mf][0..1]) + wave max per agent ----
#pragma unroll
        for (int mf = 0; mf < 4; ++mf) {
            int4 mv = *(const int4*)(mask + m0 + wm * 64 + mf * 16 + g * 4);
            int mvr[4] = {mv.x, mv.y, mv.z, mv.w};
#pragma unroll
            for (int sf = 0; sf < 2; ++sf)
#pragma unroll
                for (int r = 0; r < 4; ++r)
                    sc2[mf][sf][r] = (mvr[r] > 0) ? acc[mf][sf][r] * 0.125f : -1.0e9f;
        }
#pragma unroll
        for (int sf = 0; sf < 2; ++sf) {
            float m = sc2[0][sf][0];
#pragma unroll
            for (int mf = 0; mf < 4; ++mf)
#pragma unroll
                for (int r = 0; r < 4; ++r) m = fmaxf(m, sc2[mf][sf][r]);
            m = fmaxf(m, __shfl_xor(m, 16));
            m = fmaxf(m, __shfl_xor(m, 32));
            if (g == 0) redM[wm * 32 + sf * 16 + lr] = m;
        }
    }
    __syncthreads();    // redM + Ev visible

    if (wn == 1) {
        // ---- block max, P = exp(s-Mb) -> P LDS (u16x4), L partials ----
        float le[2] = {0.f, 0.f};
#pragma unroll
        for (int sf = 0; sf < 2; ++sf) {
            int ag = sf * 16 + lr;
            Mb[sf] = fmaxf(redM[ag], redM[32 + ag]);
        }
        unsigned char* Ph = Ph0 + wm * 4608;
#pragma unroll
        for (int mf = 0; mf < 4; ++mf)
#pragma unroll
            for (int sf = 0; sf < 2; ++sf) {
                u16x4 p4;
#pragma unroll
                for (int r = 0; r < 4; ++r) {
                    float p = __expf(sc2[mf][sf][r] - Mb[sf]);
                    le[sf] += p;
                    p4[r] = f2bf(p);
                }
                int ag = sf * 16 + lr;
                *(u16x4*)(Ph + ag * 144 + mf * 32 + g * 8) = p4;
            }
#pragma unroll
        for (int sf = 0; sf < 2; ++sf) {
            le[sf] += __shfl_xor(le[sf], 16);
            le[sf] += __shfl_xor(le[sf], 32);
            if (g == 0) redL[wm * 32 + sf * 16 + lr] = le[sf];
        }
    }
    __syncthreads();    // P + redL visible

    // ---- PV: each wave one K=32 slice (half=wm, ks-sub=wn) ----
    const unsigned char* Ph = Ph0 + wm * 4608;
    const unsigned char* Ev = Evh + wm * 9216;
    bf16x8 pa[2];
#pragma unroll
    for (int agf = 0; agf < 2; ++agf) {
        int ag = agf * 16 + lr;
        pa[agf] = *(const bf16x8*)(Ph + ag * 144 + wn * 64 + g * 16);
    }
    f32x4 pv[2][4] = {};
#pragma unroll
    for (int vf = 0; vf < 4; ++vf) {
        int d5 = vf * 16 + lr;
        bf16x8 bv = *(const bf16x8*)(Ev + d5 * 144 + wn * 64 + g * 16);
#pragma unroll
        for (int agf = 0; agf < 2; ++agf)
            pv[agf][vf] = MFMA16(pa[agf], bv, pv[agf][vf]);
    }
    __syncthreads();    // PV reads done; safe to overlay avsH

    // ---- cross-wave PV reduce (2 rounds of 16 agents), f32 out ----
    float* pout = part_pv + ((size_t)bh * 128 + chunk) * 2048;
#pragma unroll
    for (int agf = 0; agf < 2; ++agf) {
#pragma unroll
        for (int vf = 0; vf < 4; ++vf)
#pragma unroll
            for (int r = 0; r < 4; ++r)
                avsH[wid * 1024 + (g * 4 + r) * 64 + vf * 16 + lr] = pv[agf][vf][r];
        __syncthreads();
#pragma unroll
        for (int j = 0; j < 4; ++j) {
            int idx = tid + 256 * j;
            pout[agf * 1024 + idx] = avsH[idx] + avsH[1024 + idx] +
                                     avsH[2048 + idx] + avsH[3072 + idx];
        }
        if (agf == 0) __syncthreads();
    }
    // ---- M,L partials ----
    if (wid == 1 && g == 0) {
        size_t o = ((size_t)bh * 128 + chunk) * 64;
        float L0 = redL[lr] + redL[32 + lr];
        float L1 = redL[16 + lr] + redL[48 + lr];
        part_ml[o + lr * 2] = Mb[0];
        part_ml[o + lr * 2 + 1] = L0;
        part_ml[o + (16 + lr) * 2] = Mb[1];
        part_ml[o + (16 + lr) * 2 + 1] = L1;
    }
}

// ------------------------------- k_agent_comb --------------------------------
// merge 128 chunks per (b,h). grid (8 agent-groups, 32 bh), block 256.
// R14: one wave per agent — parallel M/L via shfl butterfly, scl lane-wise
// (no barrier needed), dual-accumulator unroll-8 main reduce.
__global__ __launch_bounds__(256) void k_agent_comb(const float* __restrict__ part_pv,
                                                    const float* __restrict__ part_ml,
                                                    unsigned short* __restrict__ avbf) {
    __shared__ float scl[4][128];
    const int tid = threadIdx.x;
    const int ag0 = blockIdx.x * 4, bh = blockIdx.y;
    const int agl = tid >> 6;           // 0..3 : one wave per agent
    const int lane = tid & 63;
    const int ag = ag0 + agl;
    const float* mlb = part_ml + (size_t)bh * 8192 + ag * 2;

    float m0v = mlb[(size_t)lane * 64];
    float l0v = mlb[(size_t)lane * 64 + 1];
    float m1v = mlb[(size_t)(lane + 64) * 64];
    float l1v = mlb[(size_t)(lane + 64) * 64 + 1];
    float M = fmaxf(m0v, m1v);
#pragma unroll
    for (int k = 1; k < 64; k <<= 1) M = fmaxf(M, __shfl_xor(M, k));

    float e0 = __expf(m0v - M), e1 = __expf(m1v - M);
    scl[agl][lane] = e0;
    scl[agl][lane + 64] = e1;
    float L = e0 * l0v + e1 * l1v;
#pragma unroll
    for (int k = 1; k < 64; k <<= 1) L += __shfl_xor(L, k);
    const float iL = 1.0f / L;

    const int d5 = lane;
    const float* pv = part_pv + (size_t)bh * 128 * 2048 + (size_t)ag * 64 + d5;
    const float* sr = &scl[agl][0];
    float a0 = 0.f, a1 = 0.f;
#pragma unroll 8
    for (int c = 0; c < 128; c += 2) {
        a0 += sr[c] * pv[(size_t)c * 2048];
        a1 += sr[c + 1] * pv[(size_t)(c + 1) * 2048];
    }
    avbf[(size_t)bh * 2048 + (size_t)ag * 64 + d5] = f2bf((a0 + a1) * iL);
}

// ------------------------------- k_avp ----------------------------------------
// grid (4 nf-quarters, 32 bh), block 64.
__global__ __launch_bounds__(64) void k_avp(const unsigned short* __restrict__ avbf,
                                            const unsigned short* __restrict__ Wpt,
                                            unsigned char* __restrict__ AVPt) {
    const int l = threadIdx.x & 63;
    const int q = blockIdx.x, bh = blockIdx.y, b = bh >> 3, h = bh & 7;
    const int g = l >> 4, lr = l & 15;
    bf16x8 avf[2][2];
#pragma unroll
    for (int mf = 0; mf < 2; ++mf)
#pragma unroll
        for (int ks = 0; ks < 2; ++ks)
            avf[mf][ks] = *(const bf16x8*)(avbf + (size_t)bh * 2048 + (mf * 16 + lr) * 64 + ks * 32 + g * 8);
    const int kst = h >> 1;
#pragma unroll
    for (int nf = q * 8; nf < q * 8 + 8; ++nf) {
        int j = nf * 16 + lr;
        bf16x8 w0 = *(const bf16x8*)(Wpt + (size_t)j * 512 + h * 64 + g * 8);
        bf16x8 w1 = *(const bf16x8*)(Wpt + (size_t)j * 512 + h * 64 + 32 + g * 8);
        int jt = j >> 7, row = j & 127;
#pragma unroll
        for (int mf = 0; mf < 2; ++mf) {
            f32x4 z = {0.f, 0.f, 0.f, 0.f};
            f32x4 acc = MFMA16(avf[mf][0], w0, z);
            acc = MFMA16(avf[mf][1], w1, acc);
            u16x4 o;
            o[0] = f2bf(acc[0]); o[1] = f2bf(acc[1]); o[2] = f2bf(acc[2]); o[3] = f2bf(acc[3]);
            int c8 = (h & 1) * 4 + mf * 2 + (g >> 1);
            size_t byte = ((size_t)((b * 4 + jt) * 4 + kst)) * 16384 + row * 128 +
                          ((c8 ^ (row & 7)) << 4) + (g & 1) * 8;
            *(u16x4*)(AVPt + byte) = o;
        }
    }
}

// ------------------------------- k_out -----------------------------------------
__global__ __launch_bounds__(256) void k_out(const unsigned char* __restrict__ Qat,
                                             const unsigned char* __restrict__ AVPt,
                                             const int* __restrict__ mask,
                                             float* __restrict__ out) {
    __shared__ __align__(16) unsigned char As[16384];
    __shared__ __align__(16) unsigned char Bs[16384];
    const int tid = threadIdx.x, l = tid & 63, wid = tid >> 6;
    const int wm = wid >> 1, wn = wid & 1;
    const int g = l >> 4, lr = l & 15;
    const int d = blockIdx.x;
    const int nt = (d >> 3) & 3;
    const int mt = (d & 7) + ((d >> 5) << 3);
    const int m0 = mt * 128, j0 = nt * 128;
    const int b = m0 >> 14;
    f32x4 acc[4][4] = {};

    for (int ks = 0; ks < 4; ++ks) {
        const size_t abase = ((size_t)(mt * 4 + ks)) * 16384;
        const size_t bbase = ((size_t)((b * 4 + nt) * 4 + ks)) * 16384;
#pragma unroll
        for (int i = 0; i < 4; ++i) {
            gl2lds16(Qat + abase + i * 4096 + tid * 16, As + i * 4096 + tid * 16);
            gl2lds16(AVPt + bbase + i * 4096 + tid * 16, Bs + i * 4096 + tid * 16);
        }
        __syncthreads();
        bf16x8 af[4][2];
#pragma unroll
        for (int mf = 0; mf < 4; ++mf) {
            int row = wm * 64 + mf * 16 + lr;
#pragma unroll
            for (int k2 = 0; k2 < 2; ++k2)
                af[mf][k2] = *(const bf16x8*)(As + row * 128 + (((k2 * 4 + g) ^ (row & 7)) << 4));
        }
#pragma unroll
        for (int k2 = 0; k2 < 2; ++k2) {
#pragma unroll
            for (int nf = 0; nf < 4; ++nf) {
                int brow = wn * 64 + nf * 16 + lr;
                bf16x8 bv = *(const bf16x8*)(Bs + brow * 128 + (((k2 * 4 + g) ^ (brow & 7)) << 4));
#pragma unroll
                for (int mf = 0; mf < 4; ++mf)
                    acc[mf][nf] = MFMA16(af[mf][k2], bv, acc[mf][nf]);
            }
        }
        __syncthreads();
    }
#pragma unroll
    for (int mf = 0; mf < 4; ++mf) {
        int trow = m0 + wm * 64 + mf * 16 + g * 4;
#pragma unroll
        for (int r = 0; r < 4; ++r) {
            float mv = (mask[trow + r] > 0) ? 1.0f : 0.0f;
#pragma unroll
            for (int nf = 0; nf < 4; ++nf) {
                int j = j0 + wn * 64 + nf * 16 + lr;
                out[(size_t)(trow + r) * 512 + j] = acc[mf][nf][r] * mv;
            }
        }
    }
}

// ------------------------------- launch -----------------------------------------
extern "C" void kernel_launch(void* const* d_in, const int* in_sizes, int n_in,
                              void* d_out, int out_size, void* d_ws, size_t ws_size,
                              hipStream_t stream) {
    const float* x  = (const float*)d_in[0];
    const int*  mk  = (const int*)d_in[1];
    const float* at = (const float*)d_in[2];
    const float* Wq = (const float*)d_in[3];
    const float* Wk = (const float*)d_in[4];
    const float* Wv = (const float*)d_in[5];
    const float* Wp = (const float*)d_in[6];
    float* out = (float*)d_out;
    char* ws = (char*)d_ws;

    unsigned char*  xt     = (unsigned char*)(ws);                        // [0,64) tiled x
    float* part_pv = (float*)(ws + ((size_t)64 << 20));                   // [64,98) 33.5 MiB f32
    float* part_ml = (float*)(ws + ((size_t)100 << 20));                  // [100,101) 1 MiB
    unsigned char*  Qat    = (unsigned char*)(ws + ((size_t)192 << 20));  // [192,224) tiled
    unsigned short* Wpt    = (unsigned short*)(ws + ((size_t)256 << 20)); // [256,256.5)
    unsigned char*  wtl2   = (unsigned char*)(ws + ((size_t)258 << 20));  // [258,259) 1 MiB
    unsigned short* avbf   = (unsigned short*)(ws + ((size_t)259 << 20) + (576 << 10));
    unsigned char*  AVPt   = (unsigned char*)(ws + ((size_t)260 << 20));  // [260,261)

    k_cvt_x<<<2048, 256, 0, stream>>>(x, xt);
    k_w_t_p<<<dim3(16, 16), 256, 0, stream>>>(Wp, Wpt);
    k_prep<<<dim3(8, 8, 3), 256, 0, stream>>>(Wv, at, Wk, Wq, wtl2);
    k_qkvs<<<4096, 256, 0, stream>>>(xt, wtl2, mk, Qat, part_pv, part_ml);
    k_agent_comb<<<dim3(8, 32), 256, 0, stream>>>(part_pv, part_ml, avbf);
    k_avp<<<dim3(4, 32), 64, 0, stream>>>(avbf, Wpt, AVPt);
    k_out<<<2048, 256, 0, stream>>>(Qat, AVPt, mk, out);
}

// Round 17
// 203.488 us; speedup vs baseline: 1.1279x; 1.0403x over previous
//
#include <hip/hip_runtime.h>

// ---------------------------------------------------------------------------
// MaskedSuperAttention (agent attention), B=4 N=16384 C=512 H=8 HD=64 NA=32
// Math (R9): score1 = x·(Wk@a^T), score2 = x·(Wq@a^T) => Q,K,V never hit HBM.
// R17 = R14 (best anchor, 206.9us) with k_w_t_p folded into k_prep (z=3).
// R16's grid-stride cvt reverted (-5us regression; cvt was already ~5.5TB/s).
//   k_cvt_x      : x f32 -> xt bf16 TILED (R14-proven 16384-block form)
//   k_prep       : z=0: Wv -> wtl2 V ; z=1,2: Sk/Sq = W@a^T ; z=3: Wproj^T
//   k_qkvs       : GEMM x@[Wv|akw|aqw] (BN=128) ; epilogue: flash partial
//                  (M,L,PV f32) per 128-tok chunk + q-softmax -> Qat tiled.
//   k_agent_comb : merge 128 partials per (b,h) -> agent_v bf16 (wave-par)
//   k_avp        : AVP = agent_v @ Wproj -> AVPt TILED (grid 4x32)
//   k_out        : out = (Qattn @ AVPt) * keymask
// bf16 tile layout: 128x64 (16KiB); byte(row,c8)= row*128 + ((c8^(row&7))<<4)
// ---------------------------------------------------------------------------

typedef float  f32x4   __attribute__((ext_vector_type(4)));
typedef short  bf16x8  __attribute__((ext_vector_type(8)));
typedef unsigned short u16x4 __attribute__((ext_vector_type(4)));
typedef unsigned short u16x8 __attribute__((ext_vector_type(8)));

#define MFMA16(a, b, c) __builtin_amdgcn_mfma_f32_16x16x32_bf16((a), (b), (c), 0, 0, 0)

__device__ __forceinline__ unsigned short f2bf(float f) {
    unsigned u = __builtin_bit_cast(unsigned, f);
    u += 0x7FFFu + ((u >> 16) & 1u);        // RTNE
    return (unsigned short)(u >> 16);
}
__device__ __forceinline__ void gl2lds16(const void* g, void* l) {
    __builtin_amdgcn_global_load_lds(
        (const __attribute__((address_space(1))) unsigned int*)g,
        (__attribute__((address_space(3))) unsigned int*)l, 16, 0, 0);
}

// ------------------------------- k_cvt_x -----------------------------------
// R14-proven: grid 16384, block 256, one 1KB chunk per thread-group slice.
__global__ __launch_bounds__(256) void k_cvt_x(const float* __restrict__ x,
                                               unsigned char* __restrict__ xt) {
    int v = blockIdx.x * 256 + threadIdx.x;
    int tile = v >> 10;
    int q = v & 1023;
    int row = q >> 3, c = q & 7;
    int mt = tile >> 3, ks = tile & 7;
    const float* sp = x + ((size_t)(mt * 128 + row)) * 512 + ks * 64 + c * 8;
    float4 v0 = *(const float4*)sp;
    float4 v1 = *(const float4*)(sp + 4);
    u16x8 o;
    o[0] = f2bf(v0.x); o[1] = f2bf(v0.y); o[2] = f2bf(v0.z); o[3] = f2bf(v0.w);
    o[4] = f2bf(v1.x); o[5] = f2bf(v1.y); o[6] = f2bf(v1.z); o[7] = f2bf(v1.w);
    *(u16x8*)(xt + (size_t)tile * 16384 + row * 128 + ((c ^ (row & 7)) << 4)) = o;
}

// ------------------------------- k_prep --------------------------------------
// grid (8, 8, 4), block 256.
// z=0: Wv tile -> wtl2 [0,8K) of group (nt,ks)
// z=1: Sk = Wk@a^T -> [8K,12K) ; z=2: Sq = Wq@a^T -> [12K,16K)
// z=3: Wproj [k][n] -> Wpt [n][k]  (64 blocks x 4 32x32-tiles each)
__global__ __launch_bounds__(256) void k_prep(const float* __restrict__ Wv,
                                              const float* __restrict__ at,
                                              const float* __restrict__ Wk,
                                              const float* __restrict__ Wq,
                                              const float* __restrict__ Wp,
                                              unsigned char* __restrict__ wtl2,
                                              unsigned short* __restrict__ Wpt) {
    __shared__ float t[32][33];
    const int ks = blockIdx.x, nt = blockIdx.y, z = blockIdx.z;
    if (z == 0) {
        unsigned char* dst = wtl2 + ((size_t)(nt * 8 + ks)) * 16384;
        const int row = threadIdx.x & 63;
#pragma unroll
        for (int cc = 0; cc < 2; ++cc) {
            int c = (threadIdx.x >> 6) + cc * 4;
            u16x8 o;
#pragma unroll
            for (int j = 0; j < 8; ++j)
                o[j] = f2bf(Wv[(size_t)(ks * 64 + c * 8 + j) * 512 + nt * 64 + row]);
            *(u16x8*)(dst + row * 128 + ((c ^ (row & 7)) << 4)) = o;
        }
    } else if (z < 3) {
        const float* W = (z == 2) ? Wq : Wk;
        const int h = nt;
        const int row = threadIdx.x >> 3, c8 = threadIdx.x & 7;
        const float* ar = at + row * 512 + h * 64;
        float accv[8];
#pragma unroll
        for (int j = 0; j < 8; ++j) {
            const float* wr = W + (size_t)(ks * 64 + c8 * 8 + j) * 512 + h * 64;
            float s = 0.f;
#pragma unroll 8
            for (int d = 0; d < 64; ++d) s += ar[d] * wr[d];
            accv[j] = s;
        }
        u16x8 o;
#pragma unroll
        for (int j = 0; j < 8; ++j) o[j] = f2bf(accv[j]);
        *(u16x8*)(wtl2 + ((size_t)(h * 8 + ks)) * 16384 + 8192 + (z - 1) * 4096 +
                  row * 128 + ((c8 ^ (row & 7)) << 4)) = o;
    } else {
        // Wproj transpose: block (ks,nt) handles 4 tiles (ks + 8*q, nt*2 + (q&1))
        const int bidx = nt * 8 + ks;            // 0..63
#pragma unroll
        for (int q4 = 0; q4 < 4; ++q4) {
            const int tIdx = bidx * 4 + q4;       // 0..255
            const int n0 = (tIdx & 15) * 32, k0 = (tIdx >> 4) * 32;
#pragma unroll
            for (int j = 0; j < 4; ++j) {
                int i = threadIdx.x + 256 * j;
                int ky = i >> 5, nx = i & 31;
                t[ky][nx] = Wp[(size_t)(k0 + ky) * 512 + n0 + nx];
            }
            __syncthreads();
#pragma unroll
            for (int j = 0; j < 4; ++j) {
                int i = threadIdx.x + 256 * j;
                int ny = i >> 5, kx = i & 31;
                Wpt[(size_t)(n0 + ny) * 512 + k0 + kx] = f2bf(t[kx][ny]);
            }
            __syncthreads();
        }
    }
}

// ------------------------------- k_qkvs --------------------------------------
// BM=128, BN=128 (V64, Sk32, Sq32), BK=64, 2x2 wave grid (R10-proven).
// grid 4096 (XCD-swz), block 256, LDS 32768. f32 partials.
__global__ __launch_bounds__(256) void k_qkvs(const unsigned char* __restrict__ xt,
                                              const unsigned char* __restrict__ wtl2,
                                              const int* __restrict__ mask,
                                              unsigned char* __restrict__ Qat,
                                              float* __restrict__ part_pv,
                                              float* __restrict__ part_ml) {
    __shared__ __align__(16) unsigned char S_[32768];
    unsigned char* As = S_;                 // [0,16K) main A
    unsigned char* Bs = S_ + 16384;         // [16K,32K) main B
    const int tid = threadIdx.x, l = tid & 63, wid = tid >> 6;
    const int g = l >> 4, lr = l & 15;
    const int wm = wid >> 1, wn = wid & 1;
    const int dd = blockIdx.x;
    const int nt = (dd >> 3) & 7;
    const int mt = (dd & 7) + ((dd >> 6) << 3);
    const int m0 = mt * 128;
    const int b = mt >> 7, chunk = mt & 127, bh = b * 8 + nt;

    f32x4 acc[4][4] = {};

    for (int ks = 0; ks < 8; ++ks) {
        const size_t abase = ((size_t)(mt * 8 + ks)) * 16384;
        const size_t bbase = ((size_t)(nt * 8 + ks)) * 16384;
#pragma unroll
        for (int i = 0; i < 4; ++i)
            gl2lds16(xt + abase + i * 4096 + tid * 16, As + i * 4096 + tid * 16);
#pragma unroll
        for (int i = 0; i < 4; ++i)
            gl2lds16(wtl2 + bbase + i * 4096 + tid * 16, Bs + i * 4096 + tid * 16);
        __syncthreads();

        bf16x8 af[4][2];
#pragma unroll
        for (int mf = 0; mf < 4; ++mf) {
            int row = wm * 64 + mf * 16 + lr;
#pragma unroll
            for (int k2 = 0; k2 < 2; ++k2)
                af[mf][k2] = *(const bf16x8*)(As + row * 128 + (((k2 * 4 + g) ^ (row & 7)) << 4));
        }
#pragma unroll
        for (int k2 = 0; k2 < 2; ++k2) {
#pragma unroll
            for (int nf = 0; nf < 4; ++nf) {
                // wn=0: V cols (regio 0); wn=1: nf 0,1 -> Sk; nf 2,3 -> Sq
                const int regio = wn ? (8192 + (nf >> 1) * 4096) : 0;
                const int brow = (wn ? ((nf & 1) * 16) : (nf * 16)) + lr;
                bf16x8 bv = *(const bf16x8*)(Bs + regio + brow * 128 +
                                             (((k2 * 4 + g) ^ (brow & 7)) << 4));
#pragma unroll
                for (int mf = 0; mf < 4; ++mf)
                    acc[mf][nf] = MFMA16(af[mf][k2], bv, acc[mf][nf]);
            }
        }
        __syncthreads();
    }

    // ---------------- epilogue (R10-proven layout) ----------------
    // LDS: P [2 halves][32 ag][144B] @0..9216 ; Ev [2][64 d][144B] @9216..27648
    //      redM [2][32] @27648 ; redL [2][32] @27904 ; avsH overlays [0,16K).
    unsigned char* Ph0 = S_;
    unsigned char* Evh = S_ + 9216;
    float* redM = (float*)(S_ + 27648);
    float* redL = (float*)(S_ + 27904);
    float* avsH = (float*)S_;

    float sc2[4][2][4];
    float Mb[2];

    if (wn == 0) {
        // ---- V waves: acc[mf][vf] -> Ev half wm ([64 d][64 tok], stride 144) ----
        unsigned char* Ev = Evh + wm * 9216;
#pragma unroll
        for (int mf = 0; mf < 4; ++mf)
#pragma unroll
            for (int vf = 0; vf < 4; ++vf) {
                int d5 = vf * 16 + lr;
                u16x4 vv;
                vv[0] = f2bf(acc[mf][vf][0]); vv[1] = f2bf(acc[mf][vf][1]);
                vv[2] = f2bf(acc[mf][vf][2]); vv[3] = f2bf(acc[mf][vf][3]);
                *(u16x4*)(Ev + d5 * 144 + mf * 32 + g * 8) = vv;
            }
    } else {
        // ---- score waves: q-softmax from Sq (acc[mf][2..3]) -> Qat tiled ----
        const size_t qbase = ((size_t)(mt * 4 + (nt >> 1))) * 16384;
        const int c80 = (nt & 1) * 4 + (lr >> 3);
#pragma unroll
        for (int mf = 0; mf < 4; ++mf) {
#pragma unroll
            for (int r = 0; r < 4; ++r) {
                float v0 = acc[mf][2][r] * 0.125f, v1 = acc[mf][3][r] * 0.125f;
                float m = fmaxf(v0, v1);
                m = fmaxf(m, __shfl_xor(m, 1));
                m = fmaxf(m, __shfl_xor(m, 2));
                m = fmaxf(m, __shfl_xor(m, 4));
                m = fmaxf(m, __shfl_xor(m, 8));
                float e0 = __expf(v0 - m), e1 = __expf(v1 - m);
                float s = e0 + e1;
                s += __shfl_xor(s, 1);
                s += __shfl_xor(s, 2);
                s += __shfl_xor(s, 4);
                s += __shfl_xor(s, 8);
                float inv = 1.0f / s;
                int row = wm * 64 + mf * 16 + g * 4 + r;
                size_t rb = qbase + row * 128 + (lr & 7) * 2;
                *(unsigned short*)(Qat + rb + ((c80 ^ (row & 7)) << 4)) = f2bf(e0 * inv);
                *(unsigned short*)(Qat + rb + (((c80 + 2) ^ (row & 7)) << 4)) = f2bf(e1 * inv);
            }
        }
        // ---- masked key scores (acc[mf][0..1]) + wave max per agent ----
#pragma unroll
        for (int mf = 0; mf < 4; ++mf) {
            int4 mv = *(const int4*)(mask + m0 + wm * 64 + mf * 16 + g * 4);
            int mvr[4] = {mv.x, mv.y, mv.z, mv.w};
#pragma unroll
            for (int sf = 0; sf < 2; ++sf)
#pragma unroll
                for (int r = 0; r < 4; ++r)
                    sc2[mf][sf][r] = (mvr[r] > 0) ? acc[mf][sf][r] * 0.125f : -1.0e9f;
        }
#pragma unroll
        for (int sf = 0; sf < 2; ++sf) {
            float m = sc2[0][sf][0];
#pragma unroll
            for (int mf = 0; mf < 4; ++mf)
#pragma unroll
                for (int r = 0; r < 4; ++r) m = fmaxf(m, sc2[mf][sf][r]);
            m = fmaxf(m, __shfl_xor(m, 16));
            m = fmaxf(m, __shfl_xor(m, 32));
            if (g == 0) redM[wm * 32 + sf * 16 + lr] = m;
        }
    }
    __syncthreads();    // redM + Ev visible

    if (wn == 1) {
        // ---- block max, P = exp(s-Mb) -> P LDS (u16x4), L partials ----
        float le[2] = {0.f, 0.f};
#pragma unroll
        for (int sf = 0; sf < 2; ++sf) {
            int ag = sf * 16 + lr;
            Mb[sf] = fmaxf(redM[ag], redM[32 + ag]);
        }
        unsigned char* Ph = Ph0 + wm * 4608;
#pragma unroll
        for (int mf = 0; mf < 4; ++mf)
#pragma unroll
            for (int sf = 0; sf < 2; ++sf) {
                u16x4 p4;
#pragma unroll
                for (int r = 0; r < 4; ++r) {
                    float p = __expf(sc2[mf][sf][r] - Mb[sf]);
                    le[sf] += p;
                    p4[r] = f2bf(p);
                }
                int ag = sf * 16 + lr;
                *(u16x4*)(Ph + ag * 144 + mf * 32 + g * 8) = p4;
            }
#pragma unroll
        for (int sf = 0; sf < 2; ++sf) {
            le[sf] += __shfl_xor(le[sf], 16);
            le[sf] += __shfl_xor(le[sf], 32);
            if (g == 0) redL[wm * 32 + sf * 16 + lr] = le[sf];
        }
    }
    __syncthreads();    // P + redL visible

    // ---- PV: each wave one K=32 slice (half=wm, ks-sub=wn) ----
    const unsigned char* Ph = Ph0 + wm * 4608;
    const unsigned char* Ev = Evh + wm * 9216;
    bf16x8 pa[2];
#pragma unroll
    for (int agf = 0; agf < 2; ++agf) {
        int ag = agf * 16 + lr;
        pa[agf] = *(const bf16x8*)(Ph + ag * 144 + wn * 64 + g * 16);
    }
    f32x4 pv[2][4] = {};
#pragma unroll
    for (int vf = 0; vf < 4; ++vf) {
        int d5 = vf * 16 + lr;
        bf16x8 bv = *(const bf16x8*)(Ev + d5 * 144 + wn * 64 + g * 16);
#pragma unroll
        for (int agf = 0; agf < 2; ++agf)
            pv[agf][vf] = MFMA16(pa[agf], bv, pv[agf][vf]);
    }
    __syncthreads();    // PV reads done; safe to overlay avsH

    // ---- cross-wave PV reduce (2 rounds of 16 agents), f32 out ----
    float* pout = part_pv + ((size_t)bh * 128 + chunk) * 2048;
#pragma unroll
    for (int agf = 0; agf < 2; ++agf) {
#pragma unroll
        for (int vf = 0; vf < 4; ++vf)
#pragma unroll
            for (int r = 0; r < 4; ++r)
                avsH[wid * 1024 + (g * 4 + r) * 64 + vf * 16 + lr] = pv[agf][vf][r];
        __syncthreads();
#pragma unroll
        for (int j = 0; j < 4; ++j) {
            int idx = tid + 256 * j;
            pout[agf * 1024 + idx] = avsH[idx] + avsH[1024 + idx] +
                                     avsH[2048 + idx] + avsH[3072 + idx];
        }
        if (agf == 0) __syncthreads();
    }
    // ---- M,L partials ----
    if (wid == 1 && g == 0) {
        size_t o = ((size_t)bh * 128 + chunk) * 64;
        float L0 = redL[lr] + redL[32 + lr];
        float L1 = redL[16 + lr] + redL[48 + lr];
        part_ml[o + lr * 2] = Mb[0];
        part_ml[o + lr * 2 + 1] = L0;
        part_ml[o + (16 + lr) * 2] = Mb[1];
        part_ml[o + (16 + lr) * 2 + 1] = L1;
    }
}

// ------------------------------- k_agent_comb --------------------------------
// merge 128 chunks per (b,h). grid (8 agent-groups, 32 bh), block 256.
// One wave per agent — parallel M/L via shfl butterfly, scl lane-wise
// (no barrier needed), dual-accumulator unroll-8 main reduce.
__global__ __launch_bounds__(256) void k_agent_comb(const float* __restrict__ part_pv,
                                                    const float* __restrict__ part_ml,
                                                    unsigned short* __restrict__ avbf) {
    __shared__ float scl[4][128];
    const int tid = threadIdx.x;
    const int ag0 = blockIdx.x * 4, bh = blockIdx.y;
    const int agl = tid >> 6;           // 0..3 : one wave per agent
    const int lane = tid & 63;
    const int ag = ag0 + agl;
    const float* mlb = part_ml + (size_t)bh * 8192 + ag * 2;

    float m0v = mlb[(size_t)lane * 64];
    float l0v = mlb[(size_t)lane * 64 + 1];
    float m1v = mlb[(size_t)(lane + 64) * 64];
    float l1v = mlb[(size_t)(lane + 64) * 64 + 1];
    float M = fmaxf(m0v, m1v);
#pragma unroll
    for (int k = 1; k < 64; k <<= 1) M = fmaxf(M, __shfl_xor(M, k));

    float e0 = __expf(m0v - M), e1 = __expf(m1v - M);
    scl[agl][lane] = e0;
    scl[agl][lane + 64] = e1;
    float L = e0 * l0v + e1 * l1v;
#pragma unroll
    for (int k = 1; k < 64; k <<= 1) L += __shfl_xor(L, k);
    const float iL = 1.0f / L;

    const int d5 = lane;
    const float* pv = part_pv + (size_t)bh * 128 * 2048 + (size_t)ag * 64 + d5;
    const float* sr = &scl[agl][0];
    float a0 = 0.f, a1 = 0.f;
#pragma unroll 8
    for (int c = 0; c < 128; c += 2) {
        a0 += sr[c] * pv[(size_t)c * 2048];
        a1 += sr[c + 1] * pv[(size_t)(c + 1) * 2048];
    }
    avbf[(size_t)bh * 2048 + (size_t)ag * 64 + d5] = f2bf((a0 + a1) * iL);
}

// ------------------------------- k_avp ----------------------------------------
// grid (4 nf-quarters, 32 bh), block 64.
__global__ __launch_bounds__(64) void k_avp(const unsigned short* __restrict__ avbf,
                                            const unsigned short* __restrict__ Wpt,
                                            unsigned char* __restrict__ AVPt) {
    const int l = threadIdx.x & 63;
    const int q = blockIdx.x, bh = blockIdx.y, b = bh >> 3, h = bh & 7;
    const int g = l >> 4, lr = l & 15;
    bf16x8 avf[2][2];
#pragma unroll
    for (int mf = 0; mf < 2; ++mf)
#pragma unroll
        for (int ks = 0; ks < 2; ++ks)
            avf[mf][ks] = *(const bf16x8*)(avbf + (size_t)bh * 2048 + (mf * 16 + lr) * 64 + ks * 32 + g * 8);
    const int kst = h >> 1;
#pragma unroll
    for (int nf = q * 8; nf < q * 8 + 8; ++nf) {
        int j = nf * 16 + lr;
        bf16x8 w0 = *(const bf16x8*)(Wpt + (size_t)j * 512 + h * 64 + g * 8);
        bf16x8 w1 = *(const bf16x8*)(Wpt + (size_t)j * 512 + h * 64 + 32 + g * 8);
        int jt = j >> 7, row = j & 127;
#pragma unroll
        for (int mf = 0; mf < 2; ++mf) {
            f32x4 z = {0.f, 0.f, 0.f, 0.f};
            f32x4 acc = MFMA16(avf[mf][0], w0, z);
            acc = MFMA16(avf[mf][1], w1, acc);
            u16x4 o;
            o[0] = f2bf(acc[0]); o[1] = f2bf(acc[1]); o[2] = f2bf(acc[2]); o[3] = f2bf(acc[3]);
            int c8 = (h & 1) * 4 + mf * 2 + (g >> 1);
            size_t byte = ((size_t)((b * 4 + jt) * 4 + kst)) * 16384 + row * 128 +
                          ((c8 ^ (row & 7)) << 4) + (g & 1) * 8;
            *(u16x4*)(AVPt + byte) = o;
        }
    }
}

// ------------------------------- k_out -----------------------------------------
__global__ __launch_bounds__(256) void k_out(const unsigned char* __restrict__ Qat,
                                             const unsigned char* __restrict__ AVPt,
                                             const int* __restrict__ mask,
                                             float* __restrict__ out) {
    __shared__ __align__(16) unsigned char As[16384];
    __shared__ __align__(16) unsigned char Bs[16384];
    const int tid = threadIdx.x, l = tid & 63, wid = tid >> 6;
    const int wm = wid >> 1, wn = wid & 1;
    const int g = l >> 4, lr = l & 15;
    const int d = blockIdx.x;
    const int nt = (d >> 3) & 3;
    const int mt = (d & 7) + ((d >> 5) << 3);
    const int m0 = mt * 128, j0 = nt * 128;
    const int b = m0 >> 14;
    f32x4 acc[4][4] = {};

    for (int ks = 0; ks < 4; ++ks) {
        const size_t abase = ((size_t)(mt * 4 + ks)) * 16384;
        const size_t bbase = ((size_t)((b * 4 + nt) * 4 + ks)) * 16384;
#pragma unroll
        for (int i = 0; i < 4; ++i) {
            gl2lds16(Qat + abase + i * 4096 + tid * 16, As + i * 4096 + tid * 16);
            gl2lds16(AVPt + bbase + i * 4096 + tid * 16, Bs + i * 4096 + tid * 16);
        }
        __syncthreads();
        bf16x8 af[4][2];
#pragma unroll
        for (int mf = 0; mf < 4; ++mf) {
            int row = wm * 64 + mf * 16 + lr;
#pragma unroll
            for (int k2 = 0; k2 < 2; ++k2)
                af[mf][k2] = *(const bf16x8*)(As + row * 128 + (((k2 * 4 + g) ^ (row & 7)) << 4));
        }
#pragma unroll
        for (int k2 = 0; k2 < 2; ++k2) {
#pragma unroll
            for (int nf = 0; nf < 4; ++nf) {
                int brow = wn * 64 + nf * 16 + lr;
                bf16x8 bv = *(const bf16x8*)(Bs + brow * 128 + (((k2 * 4 + g) ^ (brow & 7)) << 4));
#pragma unroll
                for (int mf = 0; mf < 4; ++mf)
                    acc[mf][nf] = MFMA16(af[mf][k2], bv, acc[mf][nf]);
            }
        }
        __syncthreads();
    }
#pragma unroll
    for (int mf = 0; mf < 4; ++mf) {
        int trow = m0 + wm * 64 + mf * 16 + g * 4;
#pragma unroll
        for (int r = 0; r < 4; ++r) {
            float mv = (mask[trow + r] > 0) ? 1.0f : 0.0f;
#pragma unroll
            for (int nf = 0; nf < 4; ++nf) {
                int j = j0 + wn * 64 + nf * 16 + lr;
                out[(size_t)(trow + r) * 512 + j] = acc[mf][nf][r] * mv;
            }
        }
    }
}

// ------------------------------- launch -----------------------------------------
extern "C" void kernel_launch(void* const* d_in, const int* in_sizes, int n_in,
                              void* d_out, int out_size, void* d_ws, size_t ws_size,
                              hipStream_t stream) {
    const float* x  = (const float*)d_in[0];
    const int*  mk  = (const int*)d_in[1];
    const float* at = (const float*)d_in[2];
    const float* Wq = (const float*)d_in[3];
    const float* Wk = (const float*)d_in[4];
    const float* Wv = (const float*)d_in[5];
    const float* Wp = (const float*)d_in[6];
    float* out = (float*)d_out;
    char* ws = (char*)d_ws;

    unsigned char*  xt     = (unsigned char*)(ws);                        // [0,64) tiled x
    float* part_pv = (float*)(ws + ((size_t)64 << 20));                   // [64,98) 33.5 MiB f32
    float* part_ml = (float*)(ws + ((size_t)100 << 20));                  // [100,101) 1 MiB
    unsigned char*  Qat    = (unsigned char*)(ws + ((size_t)192 << 20));  // [192,224) tiled
    unsigned short* Wpt    = (unsigned short*)(ws + ((size_t)256 << 20)); // [256,256.5)
    unsigned char*  wtl2   = (unsigned char*)(ws + ((size_t)258 << 20));  // [258,259) 1 MiB
    unsigned short* avbf   = (unsigned short*)(ws + ((size_t)259 << 20) + (576 << 10));
    unsigned char*  AVPt   = (unsigned char*)(ws + ((size_t)260 << 20));  // [260,261)

    k_cvt_x<<<16384, 256, 0, stream>>>(x, xt);
    k_prep<<<dim3(8, 8, 4), 256, 0, stream>>>(Wv, at, Wk, Wq, Wp, wtl2, Wpt);
    k_qkvs<<<4096, 256, 0, stream>>>(xt, wtl2, mk, Qat, part_pv, part_ml);
    k_agent_comb<<<dim3(8, 32), 256, 0, stream>>>(part_pv, part_ml, avbf);
    k_avp<<<dim3(4, 32), 64, 0, stream>>>(avbf, Wpt, AVPt);
    k_out<<<2048, 256, 0, stream>>>(Qat, AVPt, mk, out);
}